// Round 20
// baseline (310.362 us; speedup 1.0000x reference)
//
#include <hip/hip_runtime.h>
#include <hip/hip_fp16.h>

constexpr int NN = 100000;   // nodes
constexpr int NE = 3200000;  // edges
constexpr int NG = 256;      // graphs
constexpr int NCB = 391;     // coarse buckets: dst>>8 (256 nodes each; 99999>>8 = 390)
constexpr int TILE = 4096;   // edges per msplit block
constexpr int EPT = TILE / 256;
constexpr int CAP = 9216;    // per-bucket slot capacity (mean 8184 + ~11 sigma)
constexpr int L1_BLOCKS = 2048;             // grid-stride blocks for l1fused
constexpr int L1_WAVES = L1_BLOCKS * 4;     // 8192 waves

// ---------- zero helper ----------
__global__ void k_zero_i(int* __restrict__ p, int n) {
  int i = blockIdx.x * blockDim.x + threadIdx.x;
  if (i < n) p[i] = 0;
}

// ---------- CSR pass 1: multisplit, int4 edge loads, parallel lbase scan ----------
__global__ void k_msplit(const int* __restrict__ src, const int* __restrict__ dst,
                         int* __restrict__ gcursor, int* __restrict__ pairs, int E) {
  constexpr int NT = 256;
  __shared__ int hist[512], lbase[512], lcur[NCB], gwrite[NCB];
  __shared__ unsigned short sbid[TILE];
  __shared__ int staged[TILE];
  __shared__ int s[256];
  const int tid = threadIdx.x;
  const int e0 = blockIdx.x * TILE;
  for (int i = tid; i < 512; i += NT) hist[i] = 0;
  for (int i = tid; i < NCB; i += NT) lcur[i] = 0;
  __syncthreads();
  int4 ls[EPT / 4], ld[EPT / 4];
  bool valid[EPT / 4];
#pragma unroll
  for (int j = 0; j < EPT / 4; ++j) {
    int e = e0 + j * (NT * 4) + tid * 4;
    valid[j] = (e < E);
    if (valid[j]) {
      ls[j] = *(const int4*)(src + e);
      ld[j] = *(const int4*)(dst + e);
      atomicAdd(&hist[ld[j].x >> 8], 1);
      atomicAdd(&hist[ld[j].y >> 8], 1);
      atomicAdd(&hist[ld[j].z >> 8], 1);
      atomicAdd(&hist[ld[j].w >> 8], 1);
    }
  }
  __syncthreads();
  // parallel exclusive scan of hist[0..511] (2 entries/thread)
  int h0 = hist[2 * tid], h1 = hist[2 * tid + 1];
  s[tid] = h0 + h1;
  __syncthreads();
  for (int o = 1; o < 256; o <<= 1) {
    int v = s[tid];
    int u = (tid >= o) ? s[tid - o] : 0;
    __syncthreads();
    s[tid] = v + u;
    __syncthreads();
  }
  int p2 = (tid == 0) ? 0 : s[tid - 1];
  lbase[2 * tid] = p2;
  lbase[2 * tid + 1] = p2 + h0;
  __syncthreads();
  for (int c = tid; c < NCB; c += NT) {
    int cnt = hist[c];
    if (cnt > 0) {
      int g = atomicAdd(&gcursor[c], cnt);
      gwrite[c] = c * CAP + g;
    }
  }
  __syncthreads();
#pragma unroll
  for (int j = 0; j < EPT / 4; ++j) {
    if (valid[j]) {
      int ss[4] = {ls[j].x, ls[j].y, ls[j].z, ls[j].w};
      int dd[4] = {ld[j].x, ld[j].y, ld[j].z, ld[j].w};
#pragma unroll
      for (int q = 0; q < 4; ++q) {
        int c = dd[q] >> 8;
        int pos = lbase[c] + atomicAdd(&lcur[c], 1);
        staged[pos] = ss[q] | ((dd[q] & 255) << 17);
        sbid[pos] = (unsigned short)c;
      }
    }
  }
  __syncthreads();
  const int total = (e0 + TILE <= E) ? TILE : (E - e0);
  for (int i = tid; i < total; i += NT) {
    int c = sbid[i];
    pairs[gwrite[c] + (i - lbase[c])] = staged[i];
  }
}

// ---------- CSR pass 2: 256-node buckets; inline cbase prefix + deg + scan + fill ----------
__global__ void k_brow(const int* __restrict__ pairs, const int* __restrict__ gcursor,
                       int* __restrict__ rowstart, float* __restrict__ dinv,
                       int* __restrict__ csr_src) {
  __shared__ int deg[256], pre[256], cur[256];
  __shared__ int cbaseL[512];
  __shared__ int s[256];
  const int cb = blockIdx.x;
  const int n0 = cb << 8;
  const int tid = threadIdx.x;
  int g0 = (2 * tid < NCB) ? gcursor[2 * tid] : 0;
  int g1 = (2 * tid + 1 < NCB) ? gcursor[2 * tid + 1] : 0;
  s[tid] = g0 + g1;
  __syncthreads();
  for (int o = 1; o < 256; o <<= 1) {
    int v = s[tid];
    int u = (tid >= o) ? s[tid - o] : 0;
    __syncthreads();
    s[tid] = v + u;
    __syncthreads();
  }
  int p2 = (tid == 0) ? 0 : s[tid - 1];
  cbaseL[2 * tid] = p2;
  cbaseL[2 * tid + 1] = p2 + g0;
  __syncthreads();
  const int e0 = cbaseL[cb];
  const int cnt = gcursor[cb];
  const int p0 = cb * CAP;
  deg[tid] = 0;
  cur[tid] = 0;
  __syncthreads();
  for (int e = tid; e < cnt; e += 256) atomicAdd(&deg[(pairs[p0 + e] >> 17) & 255], 1);
  __syncthreads();
  int d = deg[tid];
  s[tid] = d;
  __syncthreads();
  for (int o = 1; o < 256; o <<= 1) {
    int v = s[tid];
    int u = (tid >= o) ? s[tid - o] : 0;
    __syncthreads();
    s[tid] = v + u;
    __syncthreads();
  }
  pre[tid] = (tid == 0) ? 0 : s[tid - 1];
  __syncthreads();
  const int n = n0 + tid;
  if (n < NN) {
    rowstart[n] = e0 + pre[tid];
    dinv[n] = rsqrtf((float)(d + 1));
  }
  if (cb == NCB - 1 && tid == 0) rowstart[NN] = NE;
  for (int e = tid; e < cnt; e += 256) {
    int w = pairs[p0 + e];
    int dl = (w >> 17) & 255;
    int p = e0 + pre[dl] + atomicAdd(&cur[dl], 1);
    csr_src[p] = w & 0x1FFFF;
  }
}

// ---------- xs = x * dinv (fp16), padded 13 -> 16 ----------
__global__ void k_xs(const float* __restrict__ x, const float* __restrict__ dinv,
                     __half* __restrict__ xs) {
  int i = blockIdx.x * blockDim.x + threadIdx.x;
  if (i < NN * 16) {
    int v = i >> 4, f = i & 15;
    float val = (f < 13) ? x[v * 13 + f] * dinv[v] : 0.0f;
    xs[i] = __float2half_rn(val);
  }
}

// ---------- layer 1 fused, W2 in registers, grid-stride; t2 fp16 ----------
__global__ void __launch_bounds__(256, 4) k_l1fused(
    const __half* __restrict__ xs, const int* __restrict__ rowstart,
    const int* __restrict__ csr_src, const float* __restrict__ dinv,
    const float* __restrict__ W1, const float* __restrict__ b1,
    const float* __restrict__ W2, __half* __restrict__ t2) {
  __shared__ float W1s[13 * 64];
  __shared__ float B1s[64];
  __shared__ float aggs[4][16];
  __shared__ float h1s[4][64];
  __shared__ int lidx[4][64];
  const int tid = threadIdx.x;
  for (int i = tid; i < 13 * 64; i += 256) W1s[i] = W1[i];
  if (tid < 64) B1s[tid] = b1[tid];
  const int wv = tid >> 6;
  const int lane = tid & 63;
  const int c4 = lane & 15, kh = lane >> 4;
  float w2r[16][4];
#pragma unroll
  for (int i = 0; i < 16; ++i) {
    float4 v = *(const float4*)(W2 + (kh * 16 + i) * 64 + c4 * 4);
    w2r[i][0] = v.x; w2r[i][1] = v.y; w2r[i][2] = v.z; w2r[i][3] = v.w;
  }
  __syncthreads();  // W1s/B1s ready; only barrier
  const int fp = lane & 7;
  const int es = lane >> 3;
  const __half2* x2 = (const __half2*)xs;
  for (int node = blockIdx.x * 4 + wv; node < NN; node += L1_WAVES) {
    const int r0 = rowstart[node], r1 = rowstart[node + 1];
    float ax = 0.0f, ay = 0.0f;
    if (es == 0) {
      float2 sf = __half22float2(x2[node * 8 + fp]);
      ax = sf.x; ay = sf.y;
    }
    for (int base = r0; base < r1; base += 64) {
      const int nc = min(64, r1 - base);
      lidx[wv][lane] = (base + lane < r1) ? csr_src[base + lane] : 0;
      int i = es;
      for (; i + 24 < nc; i += 32) {
        int s0 = lidx[wv][i], s1 = lidx[wv][i + 8], s2 = lidx[wv][i + 16], s3 = lidx[wv][i + 24];
        float2 v0 = __half22float2(x2[s0 * 8 + fp]);
        float2 v1 = __half22float2(x2[s1 * 8 + fp]);
        float2 v2 = __half22float2(x2[s2 * 8 + fp]);
        float2 v3 = __half22float2(x2[s3 * 8 + fp]);
        ax += (v0.x + v1.x) + (v2.x + v3.x);
        ay += (v0.y + v1.y) + (v2.y + v3.y);
      }
      for (; i < nc; i += 8) {
        int s = lidx[wv][i];
        float2 v = __half22float2(x2[s * 8 + fp]);
        ax += v.x; ay += v.y;
      }
    }
    ax += __shfl_xor(ax, 32); ay += __shfl_xor(ay, 32);
    ax += __shfl_xor(ax, 16); ay += __shfl_xor(ay, 16);
    ax += __shfl_xor(ax, 8);  ay += __shfl_xor(ay, 8);
    const float di = dinv[node];
    if (lane < 8) {
      aggs[wv][2 * fp]     = ax * di;
      aggs[wv][2 * fp + 1] = ay * di;
    }
    float acc = B1s[lane];
#pragma unroll
    for (int k = 0; k < 13; ++k) acc += aggs[wv][k] * W1s[k * 64 + lane];
    h1s[wv][lane] = fmaxf(acc, 0.0f);
    float a0 = 0.0f, a1 = 0.0f, a2 = 0.0f, a3 = 0.0f;
#pragma unroll
    for (int i = 0; i < 16; ++i) {
      float hb = h1s[wv][kh * 16 + i];
      a0 += hb * w2r[i][0];
      a1 += hb * w2r[i][1];
      a2 += hb * w2r[i][2];
      a3 += hb * w2r[i][3];
    }
    a0 += __shfl_xor(a0, 16); a0 += __shfl_xor(a0, 32);
    a1 += __shfl_xor(a1, 16); a1 += __shfl_xor(a1, 32);
    a2 += __shfl_xor(a2, 16); a2 += __shfl_xor(a2, 32);
    a3 += __shfl_xor(a3, 16); a3 += __shfl_xor(a3, 32);
    if (kh == 0) {
      __half2* o = (__half2*)t2;
      o[node * 32 + c4 * 2]     = __floats2half2_rn(a0 * di, a1 * di);
      o[node * 32 + c4 * 2 + 1] = __floats2half2_rn(a2 * di, a3 * di);
    }
  }
}

// ---------- layer-2 gather + mm3; 2 edge slots x 16-deep (32 edges in flight) ----------
__global__ void __launch_bounds__(256) k_gather64m(
    const __half* __restrict__ t, const int* __restrict__ rowstart,
    const int* __restrict__ csr_src, const float* __restrict__ dinv,
    const float* __restrict__ b2, const float* __restrict__ W3,
    __half* __restrict__ t3) {
  __shared__ float W3s[64 * 32];
  __shared__ float h2s[4][64];
  __shared__ int lidx[4][64];
  const int tid = threadIdx.x;
  for (int i = tid; i < 64 * 32; i += 256) W3s[i] = W3[i];
  __syncthreads();  // W3s ready; only barrier
  const int w = tid >> 6;
  const int lane = tid & 63;
  const int node = blockIdx.x * 4 + w;
  const int fp = lane & 31;
  const int es = lane >> 5;
  const __half2* t2 = (const __half2*)t;
  const int r0 = rowstart[node], r1 = rowstart[node + 1];
  float ax = 0.0f, ay = 0.0f;
  if (es == 0) {
    float2 sf = __half22float2(t2[node * 32 + fp]);
    ax = sf.x; ay = sf.y;
  }
  for (int base = r0; base < r1; base += 64) {
    const int nc = min(64, r1 - base);
    lidx[w][lane] = (base + lane < r1) ? csr_src[base + lane] : 0;
    int i = es;
    for (; i + 30 < nc; i += 32) {  // 16 loads/lane in flight = 32 edges/wave-iter
      int s0 = lidx[w][i],      s1 = lidx[w][i + 2],  s2 = lidx[w][i + 4],  s3 = lidx[w][i + 6];
      int s4 = lidx[w][i + 8],  s5 = lidx[w][i + 10], s6 = lidx[w][i + 12], s7 = lidx[w][i + 14];
      int s8 = lidx[w][i + 16], s9 = lidx[w][i + 18], sa = lidx[w][i + 20], sb = lidx[w][i + 22];
      int sc = lidx[w][i + 24], sd = lidx[w][i + 26], se = lidx[w][i + 28], sf = lidx[w][i + 30];
      float2 v0 = __half22float2(t2[s0 * 32 + fp]);
      float2 v1 = __half22float2(t2[s1 * 32 + fp]);
      float2 v2 = __half22float2(t2[s2 * 32 + fp]);
      float2 v3 = __half22float2(t2[s3 * 32 + fp]);
      float2 v4 = __half22float2(t2[s4 * 32 + fp]);
      float2 v5 = __half22float2(t2[s5 * 32 + fp]);
      float2 v6 = __half22float2(t2[s6 * 32 + fp]);
      float2 v7 = __half22float2(t2[s7 * 32 + fp]);
      float2 v8 = __half22float2(t2[s8 * 32 + fp]);
      float2 v9 = __half22float2(t2[s9 * 32 + fp]);
      float2 va = __half22float2(t2[sa * 32 + fp]);
      float2 vb = __half22float2(t2[sb * 32 + fp]);
      float2 vc = __half22float2(t2[sc * 32 + fp]);
      float2 vd = __half22float2(t2[sd * 32 + fp]);
      float2 ve = __half22float2(t2[se * 32 + fp]);
      float2 vf = __half22float2(t2[sf * 32 + fp]);
      ax += (((v0.x + v1.x) + (v2.x + v3.x)) + ((v4.x + v5.x) + (v6.x + v7.x))) +
            (((v8.x + v9.x) + (va.x + vb.x)) + ((vc.x + vd.x) + (ve.x + vf.x)));
      ay += (((v0.y + v1.y) + (v2.y + v3.y)) + ((v4.y + v5.y) + (v6.y + v7.y))) +
            (((v8.y + v9.y) + (va.y + vb.y)) + ((vc.y + vd.y) + (ve.y + vf.y)));
    }
    for (; i < nc; i += 2) {
      int s = lidx[w][i];
      float2 v = __half22float2(t2[s * 32 + fp]);
      ax += v.x; ay += v.y;
    }
  }
  ax += __shfl_xor(ax, 32); ay += __shfl_xor(ay, 32);
  const float di = dinv[node];
  if (es == 0) {
    float2 bb = ((const float2*)b2)[fp];
    h2s[w][2 * fp]     = fmaxf(ax * di + bb.x, 0.0f);
    h2s[w][2 * fp + 1] = fmaxf(ay * di + bb.y, 0.0f);
  }
  const int j = lane & 31, kh = lane >> 5;
  float p = 0.0f;
#pragma unroll
  for (int k2 = 0; k2 < 32; ++k2) {
    int k = kh * 32 + k2;
    p += h2s[w][k] * W3s[k * 32 + j];
  }
  p += __shfl_xor(p, 32);
  if (lane < 32) t3[node * 32 + j] = __float2half_rn(p * di);
}

// ---------- layer-3 gather, LDS idx preload; 4 edge slots, 8-deep; h3 fp16 ----------
__global__ void k_gather32w(const __half* __restrict__ t, const int* __restrict__ rowstart,
                            const int* __restrict__ csr_src,
                            const float* __restrict__ dinv, const float* __restrict__ b,
                            __half* __restrict__ h3) {
  __shared__ int lidx[4][64];
  const int wv = threadIdx.x >> 6;
  const int node = (blockIdx.x * blockDim.x + threadIdx.x) >> 6;
  const int lane = threadIdx.x & 63;
  const int fp = lane & 15;
  const int es = lane >> 4;
  const __half2* t2 = (const __half2*)t;
  const int r0 = rowstart[node], r1 = rowstart[node + 1];
  float ax = 0.0f, ay = 0.0f;
  if (es == 0) {
    float2 sf = __half22float2(t2[node * 16 + fp]);
    ax = sf.x; ay = sf.y;
  }
  for (int base = r0; base < r1; base += 64) {
    const int nc = min(64, r1 - base);
    lidx[wv][lane] = (base + lane < r1) ? csr_src[base + lane] : 0;
    int i = es;
    for (; i + 28 < nc; i += 32) {
      int s0 = lidx[wv][i],      s1 = lidx[wv][i + 4],  s2 = lidx[wv][i + 8],  s3 = lidx[wv][i + 12];
      int s4 = lidx[wv][i + 16], s5 = lidx[wv][i + 20], s6 = lidx[wv][i + 24], s7 = lidx[wv][i + 28];
      float2 v0 = __half22float2(t2[s0 * 16 + fp]);
      float2 v1 = __half22float2(t2[s1 * 16 + fp]);
      float2 v2 = __half22float2(t2[s2 * 16 + fp]);
      float2 v3 = __half22float2(t2[s3 * 16 + fp]);
      float2 v4 = __half22float2(t2[s4 * 16 + fp]);
      float2 v5 = __half22float2(t2[s5 * 16 + fp]);
      float2 v6 = __half22float2(t2[s6 * 16 + fp]);
      float2 v7 = __half22float2(t2[s7 * 16 + fp]);
      ax += ((v0.x + v1.x) + (v2.x + v3.x)) + ((v4.x + v5.x) + (v6.x + v7.x));
      ay += ((v0.y + v1.y) + (v2.y + v3.y)) + ((v4.y + v5.y) + (v6.y + v7.y));
    }
    for (; i < nc; i += 4) {
      int s = lidx[wv][i];
      float2 v = __half22float2(t2[s * 16 + fp]);
      ax += v.x; ay += v.y;
    }
  }
  ax += __shfl_xor(ax, 32); ay += __shfl_xor(ay, 32);
  ax += __shfl_xor(ax, 16); ay += __shfl_xor(ay, 16);
  if (lane < 16) {
    const float di = dinv[node];
    float2 bb = ((const float2*)b)[fp];
    ((__half2*)h3)[node * 16 + fp] = __floats2half2_rn(ax * di + bb.x, ay * di + bb.y);
  }
}

// ---------- per-graph mean pool (fp16 h3, batch sorted -> contiguous ranges) ----------
__global__ void k_pool(const __half* __restrict__ h3, const int* __restrict__ batch,
                       float* __restrict__ out) {
  const int g = blockIdx.x;
  int lo = 0, hi = NN;
  while (lo < hi) { int m = (lo + hi) >> 1; if (batch[m] < g) lo = m + 1; else hi = m; }
  const int a = lo;
  lo = 0; hi = NN;
  while (lo < hi) { int m = (lo + hi) >> 1; if (batch[m] < g + 1) lo = m + 1; else hi = m; }
  const int bEnd = lo;
  const int tid = threadIdx.x;
  const int nl = tid >> 4, f = tid & 15;
  const __half2* h2p = (const __half2*)h3;
  float ax = 0.0f, ay = 0.0f;
  for (int n = a + nl; n < bEnd; n += 16) {
    float2 v = __half22float2(h2p[n * 16 + f]);
    ax += v.x; ay += v.y;
  }
  __shared__ float redx[16][16], redy[16][16];
  redx[nl][f] = ax; redy[nl][f] = ay;
  __syncthreads();
  if (tid < 16) {
    float sx = 0.0f, sy = 0.0f;
#pragma unroll
    for (int i = 0; i < 16; ++i) { sx += redx[i][tid]; sy += redy[i][tid]; }
    float inv = 1.0f / fmaxf((float)(bEnd - a), 1.0f);
    ((float2*)out)[g * 16 + tid] = make_float2(sx * inv, sy * inv);
  }
}

extern "C" void kernel_launch(void* const* d_in, const int* in_sizes, int n_in,
                              void* d_out, int out_size, void* d_ws, size_t ws_size,
                              hipStream_t stream) {
  const float* x  = (const float*)d_in[0];
  const int*   ei = (const int*)d_in[1];
  const int* batch = (const int*)d_in[2];
  const float* W1 = (const float*)d_in[3];
  const float* b1 = (const float*)d_in[4];
  const float* W2 = (const float*)d_in[5];
  const float* b2 = (const float*)d_in[6];
  const float* W3 = (const float*)d_in[7];
  const float* b3 = (const float*)d_in[8];
  float* out = (float*)d_out;

  const int* src = ei;        // edge_index[0]
  const int* dst = ei + NE;   // edge_index[1]

  // workspace layout (element offsets, 4B floats) -- extent 64.8 MB
  float* ws = (float*)d_ws;
  float* dinv     = ws;                          // NN
  int*   gcursor  = (int*)(ws + 100352);         // NCB (zeroed each call)
  int*   rowstart = (int*)(ws + 100944);         // NN+1
  int*   csr_src  = (int*)(ws + 201056);         // NE              ends 3401056
  float* bufT     = ws + 3401056;                // NN*64 floats    ends 9801056
  float* bufH     = ws + 9801056;                // NN*64 floats    ends 16201056
  // aliases (lifetimes disjoint):
  int*    pairs = (int*)bufT;                    // NCB*CAP = 3,603,456 ints, dead after brow
  __half* t2    = (__half*)bufT;                 // NN*64 halves
  __half* h3    = (__half*)(bufT + 1801728);     // NN*32 halves (after pairs region)
  __half* xs    = (__half*)bufH;                 // NN*16 halves, dead after l1fused
  __half* t3    = (__half*)bufH;                 // NN*32 halves (xs dead)

  const int B = 256;
  auto cdiv = [](int a, int b) { return (a + b - 1) / b; };

  // ---- build CSR + norm (shared across all 3 layers) ----
  k_zero_i<<<2, B, 0, stream>>>(gcursor, NCB);
  k_msplit<<<cdiv(NE, TILE), B, 0, stream>>>(src, dst, gcursor, pairs, NE);
  k_brow<<<NCB, B, 0, stream>>>(pairs, gcursor, rowstart, dinv, csr_src);

  // ---- layer 1 fused (reg-weights, grid-stride): xs -> gather+mm1+relu+mm2 -> t2 ----
  k_xs<<<cdiv(NN * 16, B), B, 0, stream>>>(x, dinv, xs);
  k_l1fused<<<L1_BLOCKS, B, 0, stream>>>(xs, rowstart, csr_src, dinv, W1, b1, W2, t2);

  // ---- layer 2 aggregation fused with mm3: t2 -> t3(fp16) ----
  k_gather64m<<<NN / 4, B, 0, stream>>>(t2, rowstart, csr_src, dinv, b2, W3, t3);

  // ---- layer 3 aggregation: t3 -> h3(fp16), then pool ----
  k_gather32w<<<cdiv(NN * 64, B), B, 0, stream>>>(t3, rowstart, csr_src, dinv, b3, h3);
  k_pool<<<NG, B, 0, stream>>>(h3, batch, out);
}

// Round 21
// 269.644 us; speedup vs baseline: 1.1510x; 1.1510x over previous
//
#include <hip/hip_runtime.h>
#include <hip/hip_fp16.h>

constexpr int NN = 100000;   // nodes
constexpr int NE = 3200000;  // edges
constexpr int NG = 256;      // graphs
constexpr int NCB = 391;     // coarse buckets: dst>>8 (256 nodes each; 99999>>8 = 390)
constexpr int TILE = 4096;   // edges per msplit block
constexpr int EPT = TILE / 256;
constexpr int CAP = 9216;    // per-bucket slot capacity (mean 8184 + ~11 sigma)
constexpr int L1_BLOCKS = 2048;             // grid-stride blocks for l1fused
constexpr int L1_WAVES = L1_BLOCKS * 4;     // 8192 waves

// ---------- zero helper ----------
__global__ void k_zero_i(int* __restrict__ p, int n) {
  int i = blockIdx.x * blockDim.x + threadIdx.x;
  if (i < n) p[i] = 0;
}

// ---------- CSR pass 1: multisplit, int4 edge loads, parallel lbase scan ----------
__global__ void k_msplit(const int* __restrict__ src, const int* __restrict__ dst,
                         int* __restrict__ gcursor, int* __restrict__ pairs, int E) {
  constexpr int NT = 256;
  __shared__ int hist[512], lbase[512], lcur[NCB], gwrite[NCB];
  __shared__ unsigned short sbid[TILE];
  __shared__ int staged[TILE];
  __shared__ int s[256];
  const int tid = threadIdx.x;
  const int e0 = blockIdx.x * TILE;
  for (int i = tid; i < 512; i += NT) hist[i] = 0;
  for (int i = tid; i < NCB; i += NT) lcur[i] = 0;
  __syncthreads();
  int4 ls[EPT / 4], ld[EPT / 4];
  bool valid[EPT / 4];
#pragma unroll
  for (int j = 0; j < EPT / 4; ++j) {
    int e = e0 + j * (NT * 4) + tid * 4;
    valid[j] = (e < E);
    if (valid[j]) {
      ls[j] = *(const int4*)(src + e);
      ld[j] = *(const int4*)(dst + e);
      atomicAdd(&hist[ld[j].x >> 8], 1);
      atomicAdd(&hist[ld[j].y >> 8], 1);
      atomicAdd(&hist[ld[j].z >> 8], 1);
      atomicAdd(&hist[ld[j].w >> 8], 1);
    }
  }
  __syncthreads();
  int h0 = hist[2 * tid], h1 = hist[2 * tid + 1];
  s[tid] = h0 + h1;
  __syncthreads();
  for (int o = 1; o < 256; o <<= 1) {
    int v = s[tid];
    int u = (tid >= o) ? s[tid - o] : 0;
    __syncthreads();
    s[tid] = v + u;
    __syncthreads();
  }
  int p2 = (tid == 0) ? 0 : s[tid - 1];
  lbase[2 * tid] = p2;
  lbase[2 * tid + 1] = p2 + h0;
  __syncthreads();
  for (int c = tid; c < NCB; c += NT) {
    int cnt = hist[c];
    if (cnt > 0) {
      int g = atomicAdd(&gcursor[c], cnt);
      gwrite[c] = c * CAP + g;
    }
  }
  __syncthreads();
#pragma unroll
  for (int j = 0; j < EPT / 4; ++j) {
    if (valid[j]) {
      int ss[4] = {ls[j].x, ls[j].y, ls[j].z, ls[j].w};
      int dd[4] = {ld[j].x, ld[j].y, ld[j].z, ld[j].w};
#pragma unroll
      for (int q = 0; q < 4; ++q) {
        int c = dd[q] >> 8;
        int pos = lbase[c] + atomicAdd(&lcur[c], 1);
        staged[pos] = ss[q] | ((dd[q] & 255) << 17);
        sbid[pos] = (unsigned short)c;
      }
    }
  }
  __syncthreads();
  const int total = (e0 + TILE <= E) ? TILE : (E - e0);
  for (int i = tid; i < total; i += NT) {
    int c = sbid[i];
    pairs[gwrite[c] + (i - lbase[c])] = staged[i];
  }
}

// ---------- CSR pass 2: 256-node buckets; inline cbase prefix + deg + scan + fill ----------
__global__ void k_brow(const int* __restrict__ pairs, const int* __restrict__ gcursor,
                       int* __restrict__ rowstart, float* __restrict__ dinv,
                       int* __restrict__ csr_src) {
  __shared__ int deg[256], pre[256], cur[256];
  __shared__ int cbaseL[512];
  __shared__ int s[256];
  const int cb = blockIdx.x;
  const int n0 = cb << 8;
  const int tid = threadIdx.x;
  int g0 = (2 * tid < NCB) ? gcursor[2 * tid] : 0;
  int g1 = (2 * tid + 1 < NCB) ? gcursor[2 * tid + 1] : 0;
  s[tid] = g0 + g1;
  __syncthreads();
  for (int o = 1; o < 256; o <<= 1) {
    int v = s[tid];
    int u = (tid >= o) ? s[tid - o] : 0;
    __syncthreads();
    s[tid] = v + u;
    __syncthreads();
  }
  int p2 = (tid == 0) ? 0 : s[tid - 1];
  cbaseL[2 * tid] = p2;
  cbaseL[2 * tid + 1] = p2 + g0;
  __syncthreads();
  const int e0 = cbaseL[cb];
  const int cnt = gcursor[cb];
  const int p0 = cb * CAP;
  deg[tid] = 0;
  cur[tid] = 0;
  __syncthreads();
  for (int e = tid; e < cnt; e += 256) atomicAdd(&deg[(pairs[p0 + e] >> 17) & 255], 1);
  __syncthreads();
  int d = deg[tid];
  s[tid] = d;
  __syncthreads();
  for (int o = 1; o < 256; o <<= 1) {
    int v = s[tid];
    int u = (tid >= o) ? s[tid - o] : 0;
    __syncthreads();
    s[tid] = v + u;
    __syncthreads();
  }
  pre[tid] = (tid == 0) ? 0 : s[tid - 1];
  __syncthreads();
  const int n = n0 + tid;
  if (n < NN) {
    rowstart[n] = e0 + pre[tid];
    dinv[n] = rsqrtf((float)(d + 1));
  }
  if (cb == NCB - 1 && tid == 0) rowstart[NN] = NE;
  for (int e = tid; e < cnt; e += 256) {
    int w = pairs[p0 + e];
    int dl = (w >> 17) & 255;
    int p = e0 + pre[dl] + atomicAdd(&cur[dl], 1);
    csr_src[p] = w & 0x1FFFF;
  }
}

// ---------- xs = x * dinv (fp16), padded 13 -> 16 ----------
__global__ void k_xs(const float* __restrict__ x, const float* __restrict__ dinv,
                     __half* __restrict__ xs) {
  int i = blockIdx.x * blockDim.x + threadIdx.x;
  if (i < NN * 16) {
    int v = i >> 4, f = i & 15;
    float val = (f < 13) ? x[v * 13 + f] * dinv[v] : 0.0f;
    xs[i] = __float2half_rn(val);
  }
}

// ---------- layer 1 fused, W2 in registers, grid-stride; t2 fp16 ----------
__global__ void __launch_bounds__(256, 4) k_l1fused(
    const __half* __restrict__ xs, const int* __restrict__ rowstart,
    const int* __restrict__ csr_src, const float* __restrict__ dinv,
    const float* __restrict__ W1, const float* __restrict__ b1,
    const float* __restrict__ W2, __half* __restrict__ t2) {
  __shared__ float W1s[13 * 64];
  __shared__ float B1s[64];
  __shared__ float aggs[4][16];
  __shared__ float h1s[4][64];
  __shared__ int lidx[4][64];
  const int tid = threadIdx.x;
  for (int i = tid; i < 13 * 64; i += 256) W1s[i] = W1[i];
  if (tid < 64) B1s[tid] = b1[tid];
  const int wv = tid >> 6;
  const int lane = tid & 63;
  const int c4 = lane & 15, kh = lane >> 4;
  float w2r[16][4];
#pragma unroll
  for (int i = 0; i < 16; ++i) {
    float4 v = *(const float4*)(W2 + (kh * 16 + i) * 64 + c4 * 4);
    w2r[i][0] = v.x; w2r[i][1] = v.y; w2r[i][2] = v.z; w2r[i][3] = v.w;
  }
  __syncthreads();  // W1s/B1s ready; only barrier
  const int fp = lane & 7;
  const int es = lane >> 3;
  const __half2* x2 = (const __half2*)xs;
  for (int node = blockIdx.x * 4 + wv; node < NN; node += L1_WAVES) {
    const int r0 = rowstart[node], r1 = rowstart[node + 1];
    float ax = 0.0f, ay = 0.0f;
    if (es == 0) {
      float2 sf = __half22float2(x2[node * 8 + fp]);
      ax = sf.x; ay = sf.y;
    }
    for (int base = r0; base < r1; base += 64) {
      const int nc = min(64, r1 - base);
      lidx[wv][lane] = (base + lane < r1) ? csr_src[base + lane] : 0;
      int i = es;
      for (; i + 24 < nc; i += 32) {
        int s0 = lidx[wv][i], s1 = lidx[wv][i + 8], s2 = lidx[wv][i + 16], s3 = lidx[wv][i + 24];
        float2 v0 = __half22float2(x2[s0 * 8 + fp]);
        float2 v1 = __half22float2(x2[s1 * 8 + fp]);
        float2 v2 = __half22float2(x2[s2 * 8 + fp]);
        float2 v3 = __half22float2(x2[s3 * 8 + fp]);
        ax += (v0.x + v1.x) + (v2.x + v3.x);
        ay += (v0.y + v1.y) + (v2.y + v3.y);
      }
      for (; i < nc; i += 8) {
        int s = lidx[wv][i];
        float2 v = __half22float2(x2[s * 8 + fp]);
        ax += v.x; ay += v.y;
      }
    }
    ax += __shfl_xor(ax, 32); ay += __shfl_xor(ay, 32);
    ax += __shfl_xor(ax, 16); ay += __shfl_xor(ay, 16);
    ax += __shfl_xor(ax, 8);  ay += __shfl_xor(ay, 8);
    const float di = dinv[node];
    if (lane < 8) {
      aggs[wv][2 * fp]     = ax * di;
      aggs[wv][2 * fp + 1] = ay * di;
    }
    float acc = B1s[lane];
#pragma unroll
    for (int k = 0; k < 13; ++k) acc += aggs[wv][k] * W1s[k * 64 + lane];
    h1s[wv][lane] = fmaxf(acc, 0.0f);
    float a0 = 0.0f, a1 = 0.0f, a2 = 0.0f, a3 = 0.0f;
#pragma unroll
    for (int i = 0; i < 16; ++i) {
      float hb = h1s[wv][kh * 16 + i];
      a0 += hb * w2r[i][0];
      a1 += hb * w2r[i][1];
      a2 += hb * w2r[i][2];
      a3 += hb * w2r[i][3];
    }
    a0 += __shfl_xor(a0, 16); a0 += __shfl_xor(a0, 32);
    a1 += __shfl_xor(a1, 16); a1 += __shfl_xor(a1, 32);
    a2 += __shfl_xor(a2, 16); a2 += __shfl_xor(a2, 32);
    a3 += __shfl_xor(a3, 16); a3 += __shfl_xor(a3, 32);
    if (kh == 0) {
      __half2* o = (__half2*)t2;
      o[node * 32 + c4 * 2]     = __floats2half2_rn(a0 * di, a1 * di);
      o[node * 32 + c4 * 2 + 1] = __floats2half2_rn(a2 * di, a3 * di);
    }
  }
}

// ---------- layer-2 gather + mm3; 8-deep main + 4-deep mid-tail + scalar ----------
__global__ void __launch_bounds__(256) k_gather64m(
    const __half* __restrict__ t, const int* __restrict__ rowstart,
    const int* __restrict__ csr_src, const float* __restrict__ dinv,
    const float* __restrict__ b2, const float* __restrict__ W3,
    __half* __restrict__ t3) {
  __shared__ float W3s[64 * 32];
  __shared__ float h2s[4][64];
  __shared__ int lidx[4][64];
  const int tid = threadIdx.x;
  for (int i = tid; i < 64 * 32; i += 256) W3s[i] = W3[i];
  __syncthreads();  // W3s ready; only barrier
  const int w = tid >> 6;
  const int lane = tid & 63;
  const int node = blockIdx.x * 4 + w;
  const int fp = lane & 31;
  const int es = lane >> 5;
  const __half2* t2 = (const __half2*)t;
  const int r0 = rowstart[node], r1 = rowstart[node + 1];
  float ax = 0.0f, ay = 0.0f;
  if (es == 0) {
    float2 sf = __half22float2(t2[node * 32 + fp]);
    ax = sf.x; ay = sf.y;
  }
  for (int base = r0; base < r1; base += 64) {
    const int nc = min(64, r1 - base);
    lidx[w][lane] = (base + lane < r1) ? csr_src[base + lane] : 0;
    int i = es;
    for (; i + 14 < nc; i += 16) {  // 8 loads/lane in flight = 16 edges/wave-iter
      int s0 = lidx[w][i],      s1 = lidx[w][i + 2],  s2 = lidx[w][i + 4],  s3 = lidx[w][i + 6];
      int s4 = lidx[w][i + 8],  s5 = lidx[w][i + 10], s6 = lidx[w][i + 12], s7 = lidx[w][i + 14];
      float2 v0 = __half22float2(t2[s0 * 32 + fp]);
      float2 v1 = __half22float2(t2[s1 * 32 + fp]);
      float2 v2 = __half22float2(t2[s2 * 32 + fp]);
      float2 v3 = __half22float2(t2[s3 * 32 + fp]);
      float2 v4 = __half22float2(t2[s4 * 32 + fp]);
      float2 v5 = __half22float2(t2[s5 * 32 + fp]);
      float2 v6 = __half22float2(t2[s6 * 32 + fp]);
      float2 v7 = __half22float2(t2[s7 * 32 + fp]);
      ax += ((v0.x + v1.x) + (v2.x + v3.x)) + ((v4.x + v5.x) + (v6.x + v7.x));
      ay += ((v0.y + v1.y) + (v2.y + v3.y)) + ((v4.y + v5.y) + (v6.y + v7.y));
    }
    for (; i + 6 < nc; i += 8) {  // mid-tail: 4 loads/lane = 8 edges/wave-iter
      int s0 = lidx[w][i],     s1 = lidx[w][i + 2];
      int s2 = lidx[w][i + 4], s3 = lidx[w][i + 6];
      float2 v0 = __half22float2(t2[s0 * 32 + fp]);
      float2 v1 = __half22float2(t2[s1 * 32 + fp]);
      float2 v2 = __half22float2(t2[s2 * 32 + fp]);
      float2 v3 = __half22float2(t2[s3 * 32 + fp]);
      ax += (v0.x + v1.x) + (v2.x + v3.x);
      ay += (v0.y + v1.y) + (v2.y + v3.y);
    }
    for (; i < nc; i += 2) {
      int s = lidx[w][i];
      float2 v = __half22float2(t2[s * 32 + fp]);
      ax += v.x; ay += v.y;
    }
  }
  ax += __shfl_xor(ax, 32); ay += __shfl_xor(ay, 32);
  const float di = dinv[node];
  if (es == 0) {
    float2 bb = ((const float2*)b2)[fp];
    h2s[w][2 * fp]     = fmaxf(ax * di + bb.x, 0.0f);
    h2s[w][2 * fp + 1] = fmaxf(ay * di + bb.y, 0.0f);
  }
  const int j = lane & 31, kh = lane >> 5;
  float p = 0.0f;
#pragma unroll
  for (int k2 = 0; k2 < 32; ++k2) {
    int k = kh * 32 + k2;
    p += h2s[w][k] * W3s[k * 32 + j];
  }
  p += __shfl_xor(p, 32);
  if (lane < 32) t3[node * 32 + j] = __float2half_rn(p * di);
}

// ---------- layer-3 gather, LDS idx preload; 4 edge slots, 8-deep; h3 fp16 ----------
__global__ void k_gather32w(const __half* __restrict__ t, const int* __restrict__ rowstart,
                            const int* __restrict__ csr_src,
                            const float* __restrict__ dinv, const float* __restrict__ b,
                            __half* __restrict__ h3) {
  __shared__ int lidx[4][64];
  const int wv = threadIdx.x >> 6;
  const int node = (blockIdx.x * blockDim.x + threadIdx.x) >> 6;
  const int lane = threadIdx.x & 63;
  const int fp = lane & 15;
  const int es = lane >> 4;
  const __half2* t2 = (const __half2*)t;
  const int r0 = rowstart[node], r1 = rowstart[node + 1];
  float ax = 0.0f, ay = 0.0f;
  if (es == 0) {
    float2 sf = __half22float2(t2[node * 16 + fp]);
    ax = sf.x; ay = sf.y;
  }
  for (int base = r0; base < r1; base += 64) {
    const int nc = min(64, r1 - base);
    lidx[wv][lane] = (base + lane < r1) ? csr_src[base + lane] : 0;
    int i = es;
    for (; i + 28 < nc; i += 32) {  // 8 loads/lane = 32 edges/wave-iter
      int s0 = lidx[wv][i],      s1 = lidx[wv][i + 4],  s2 = lidx[wv][i + 8],  s3 = lidx[wv][i + 12];
      int s4 = lidx[wv][i + 16], s5 = lidx[wv][i + 20], s6 = lidx[wv][i + 24], s7 = lidx[wv][i + 28];
      float2 v0 = __half22float2(t2[s0 * 16 + fp]);
      float2 v1 = __half22float2(t2[s1 * 16 + fp]);
      float2 v2 = __half22float2(t2[s2 * 16 + fp]);
      float2 v3 = __half22float2(t2[s3 * 16 + fp]);
      float2 v4 = __half22float2(t2[s4 * 16 + fp]);
      float2 v5 = __half22float2(t2[s5 * 16 + fp]);
      float2 v6 = __half22float2(t2[s6 * 16 + fp]);
      float2 v7 = __half22float2(t2[s7 * 16 + fp]);
      ax += ((v0.x + v1.x) + (v2.x + v3.x)) + ((v4.x + v5.x) + (v6.x + v7.x));
      ay += ((v0.y + v1.y) + (v2.y + v3.y)) + ((v4.y + v5.y) + (v6.y + v7.y));
    }
    for (; i + 12 < nc; i += 16) {  // mid-tail: 4 loads/lane = 16 edges/wave-iter
      int s0 = lidx[wv][i],     s1 = lidx[wv][i + 4];
      int s2 = lidx[wv][i + 8], s3 = lidx[wv][i + 12];
      float2 v0 = __half22float2(t2[s0 * 16 + fp]);
      float2 v1 = __half22float2(t2[s1 * 16 + fp]);
      float2 v2 = __half22float2(t2[s2 * 16 + fp]);
      float2 v3 = __half22float2(t2[s3 * 16 + fp]);
      ax += (v0.x + v1.x) + (v2.x + v3.x);
      ay += (v0.y + v1.y) + (v2.y + v3.y);
    }
    for (; i < nc; i += 4) {
      int s = lidx[wv][i];
      float2 v = __half22float2(t2[s * 16 + fp]);
      ax += v.x; ay += v.y;
    }
  }
  ax += __shfl_xor(ax, 32); ay += __shfl_xor(ay, 32);
  ax += __shfl_xor(ax, 16); ay += __shfl_xor(ay, 16);
  if (lane < 16) {
    const float di = dinv[node];
    float2 bb = ((const float2*)b)[fp];
    ((__half2*)h3)[node * 16 + fp] = __floats2half2_rn(ax * di + bb.x, ay * di + bb.y);
  }
}

// ---------- per-graph mean pool (fp16 h3, batch sorted -> contiguous ranges) ----------
__global__ void k_pool(const __half* __restrict__ h3, const int* __restrict__ batch,
                       float* __restrict__ out) {
  const int g = blockIdx.x;
  int lo = 0, hi = NN;
  while (lo < hi) { int m = (lo + hi) >> 1; if (batch[m] < g) lo = m + 1; else hi = m; }
  const int a = lo;
  lo = 0; hi = NN;
  while (lo < hi) { int m = (lo + hi) >> 1; if (batch[m] < g + 1) lo = m + 1; else hi = m; }
  const int bEnd = lo;
  const int tid = threadIdx.x;
  const int nl = tid >> 4, f = tid & 15;
  const __half2* h2p = (const __half2*)h3;
  float ax = 0.0f, ay = 0.0f;
  for (int n = a + nl; n < bEnd; n += 16) {
    float2 v = __half22float2(h2p[n * 16 + f]);
    ax += v.x; ay += v.y;
  }
  __shared__ float redx[16][16], redy[16][16];
  redx[nl][f] = ax; redy[nl][f] = ay;
  __syncthreads();
  if (tid < 16) {
    float sx = 0.0f, sy = 0.0f;
#pragma unroll
    for (int i = 0; i < 16; ++i) { sx += redx[i][tid]; sy += redy[i][tid]; }
    float inv = 1.0f / fmaxf((float)(bEnd - a), 1.0f);
    ((float2*)out)[g * 16 + tid] = make_float2(sx * inv, sy * inv);
  }
}

extern "C" void kernel_launch(void* const* d_in, const int* in_sizes, int n_in,
                              void* d_out, int out_size, void* d_ws, size_t ws_size,
                              hipStream_t stream) {
  const float* x  = (const float*)d_in[0];
  const int*   ei = (const int*)d_in[1];
  const int* batch = (const int*)d_in[2];
  const float* W1 = (const float*)d_in[3];
  const float* b1 = (const float*)d_in[4];
  const float* W2 = (const float*)d_in[5];
  const float* b2 = (const float*)d_in[6];
  const float* W3 = (const float*)d_in[7];
  const float* b3 = (const float*)d_in[8];
  float* out = (float*)d_out;

  const int* src = ei;        // edge_index[0]
  const int* dst = ei + NE;   // edge_index[1]

  // workspace layout (element offsets, 4B floats) -- extent 64.8 MB
  float* ws = (float*)d_ws;
  float* dinv     = ws;                          // NN
  int*   gcursor  = (int*)(ws + 100352);         // NCB (zeroed each call)
  int*   rowstart = (int*)(ws + 100944);         // NN+1
  int*   csr_src  = (int*)(ws + 201056);         // NE              ends 3401056
  float* bufT     = ws + 3401056;                // NN*64 floats    ends 9801056
  float* bufH     = ws + 9801056;                // NN*64 floats    ends 16201056
  // aliases (lifetimes disjoint):
  int*    pairs = (int*)bufT;                    // NCB*CAP = 3,603,456 ints, dead after brow
  __half* t2    = (__half*)bufT;                 // NN*64 halves
  __half* h3    = (__half*)(bufT + 1801728);     // NN*32 halves (after pairs region)
  __half* xs    = (__half*)bufH;                 // NN*16 halves, dead after l1fused
  __half* t3    = (__half*)bufH;                 // NN*32 halves (xs dead)

  const int B = 256;
  auto cdiv = [](int a, int b) { return (a + b - 1) / b; };

  // ---- build CSR + norm (shared across all 3 layers) ----
  k_zero_i<<<2, B, 0, stream>>>(gcursor, NCB);
  k_msplit<<<cdiv(NE, TILE), B, 0, stream>>>(src, dst, gcursor, pairs, NE);
  k_brow<<<NCB, B, 0, stream>>>(pairs, gcursor, rowstart, dinv, csr_src);

  // ---- layer 1 fused (reg-weights, grid-stride): xs -> gather+mm1+relu+mm2 -> t2 ----
  k_xs<<<cdiv(NN * 16, B), B, 0, stream>>>(x, dinv, xs);
  k_l1fused<<<L1_BLOCKS, B, 0, stream>>>(xs, rowstart, csr_src, dinv, W1, b1, W2, t2);

  // ---- layer 2 aggregation fused with mm3: t2 -> t3(fp16) ----
  k_gather64m<<<NN / 4, B, 0, stream>>>(t2, rowstart, csr_src, dinv, b2, W3, t3);

  // ---- layer 3 aggregation: t3 -> h3(fp16), then pool ----
  k_gather32w<<<cdiv(NN * 64, B), B, 0, stream>>>(t3, rowstart, csr_src, dinv, b3, h3);
  k_pool<<<NG, B, 0, stream>>>(h3, batch, out);
}